// Round 6
// baseline (386.300 us; speedup 1.0000x reference)
//
#include <hip/hip_runtime.h>
#include <math.h>

#define N_INST 131072
#define L_DIM 512
#define BAG_NUM 512
#define NUM_CLASSES 128
#define CHUNK 1024

// ---------------------------------------------------------------------------
// Kernel 1: parallel segment boundaries (batch sorted).
// ---------------------------------------------------------------------------
__global__ void boundaries_kernel(const int* __restrict__ batch,
                                  int* __restrict__ start) {
    int i = blockIdx.x * blockDim.x + threadIdx.x;
    if (i >= N_INST) return;
    int b = batch[i];
    int prev = (i == 0) ? -1 : batch[i - 1];
    for (int bb = prev + 1; bb <= b; ++bb) start[bb] = i;
    if (i == N_INST - 1) {
        for (int bb = b + 1; bb <= BAG_NUM; ++bb) start[bb] = N_INST;
    }
}

// ---------------------------------------------------------------------------
// Kernel 2: fused softmax + weighted row-sum, COLUMN-SPLIT for occupancy:
// 1024 blocks; block handles bag b = blockIdx>>1, column half ch = blockIdx&1
// (float4 cols ch*64..ch*64+63). 4 rows x 64 lanes per step, 8-way unrolled
// (32 rows/iter). Weight loads are wave-uniform (whole wave same row ->
// broadcast). Softmax recomputed per half (att segment ~1KB, L1-hot).
// Writes half-rows of bag_feat; FC is a separate kernel.
// ---------------------------------------------------------------------------
__global__ __launch_bounds__(256) void bag_accum_kernel(
        const float* __restrict__ H, const float* __restrict__ att,
        const int* __restrict__ start, float* __restrict__ bag_feat) {
    int b = blockIdx.x >> 1;
    int ch = blockIdx.x & 1;
    int tid = threadIdx.x;
    int r = tid >> 6;                 // row parity 0..3 (one wave per row)
    int c4 = (tid & 63) + 64 * ch;    // float4 column index 0..127

    int s = start[b], e = start[b + 1];

    __shared__ float red[8];
    __shared__ float wlds[CHUNK];
    __shared__ float4 part[4][64];

    // --- block max over att[s..e) ---
    float m = -3.4e38f;
    for (int i = s + tid; i < e; i += 256) m = fmaxf(m, att[i]);
    for (int off = 32; off >= 1; off >>= 1) m = fmaxf(m, __shfl_down(m, off));
    if ((tid & 63) == 0) red[tid >> 6] = m;
    __syncthreads();
    m = fmaxf(fmaxf(red[0], red[1]), fmaxf(red[2], red[3]));

    // --- block sum of exp ---
    float sum = 0.f;
    for (int i = s + tid; i < e; i += 256) sum += expf(att[i] - m);
    for (int off = 32; off >= 1; off >>= 1) sum += __shfl_down(sum, off);
    if ((tid & 63) == 0) red[4 + (tid >> 6)] = sum;
    __syncthreads();
    float inv = 1.0f / (red[4] + red[5] + red[6] + red[7]);

    // --- weighted accumulation over H half-columns ---
    float4 acc = make_float4(0.f, 0.f, 0.f, 0.f);
    const float4* __restrict__ H4 = (const float4*)H;
    for (int c0 = s; c0 < e; c0 += CHUNK) {
        int ce = min(c0 + CHUNK, e);
        __syncthreads();  // protect wlds reuse across chunks
        for (int i = c0 + tid; i < ce; i += 256)
            wlds[i - c0] = expf(att[i] - m) * inv;
        __syncthreads();
        int i = c0;
        for (; i + 32 <= ce; i += 32) {
            float w[8];
            float4 h[8];
#pragma unroll
            for (int j = 0; j < 8; ++j) w[j] = wlds[i - c0 + r + 4 * j];
#pragma unroll
            for (int j = 0; j < 8; ++j)
                h[j] = H4[(size_t)(i + r + 4 * j) * 128 + c4];
#pragma unroll
            for (int j = 0; j < 8; ++j) {
                acc.x = fmaf(w[j], h[j].x, acc.x);
                acc.y = fmaf(w[j], h[j].y, acc.y);
                acc.z = fmaf(w[j], h[j].z, acc.z);
                acc.w = fmaf(w[j], h[j].w, acc.w);
            }
        }
        for (; i + 4 <= ce; i += 4) {     // 4-row tail steps
            float w = wlds[i - c0 + r];
            float4 h = H4[(size_t)(i + r) * 128 + c4];
            acc.x = fmaf(w, h.x, acc.x);
            acc.y = fmaf(w, h.y, acc.y);
            acc.z = fmaf(w, h.z, acc.z);
            acc.w = fmaf(w, h.w, acc.w);
        }
        if (i + r < ce) {                 // final <4 rows, guarded per wave
            float w = wlds[i - c0 + r];
            float4 h = H4[(size_t)(i + r) * 128 + c4];
            acc.x = fmaf(w, h.x, acc.x);
            acc.y = fmaf(w, h.y, acc.y);
            acc.z = fmaf(w, h.z, acc.z);
            acc.w = fmaf(w, h.w, acc.w);
        }
    }

    // --- combine 4 row-parities, write half-row ---
    part[r][tid & 63] = acc;
    __syncthreads();
    if (r == 0) {
        int cl = tid & 63;
        float4 a0 = part[0][cl], a1 = part[1][cl], a2 = part[2][cl], a3 = part[3][cl];
        float4 o;
        o.x = (a0.x + a1.x) + (a2.x + a3.x);
        o.y = (a0.y + a1.y) + (a2.y + a3.y);
        o.z = (a0.z + a1.z) + (a2.z + a3.z);
        o.w = (a0.w + a1.w) + (a2.w + a3.w);
        ((float4*)bag_feat)[(size_t)b * 128 + c4] = o;
    }
}

// ---------------------------------------------------------------------------
// Kernel 3: FC epilogue. 512 blocks x 256 threads; class c = tid&127,
// K-half p = tid>>7 (256 elems each), LDS combine. bag_feat + fc1_w L2-hot.
// ---------------------------------------------------------------------------
__global__ __launch_bounds__(256) void fc_kernel(
        const float* __restrict__ bag_feat, const float* __restrict__ fc1_w,
        const float* __restrict__ fc1_b, float* __restrict__ out) {
    int b = blockIdx.x;
    int tid = threadIdx.x;
    int c = tid & 127;
    int p = tid >> 7;

    __shared__ float row[L_DIM];
    __shared__ float fcred[256];

    if (tid < 128)
        ((float4*)row)[tid] = ((const float4*)(bag_feat + (size_t)b * L_DIM))[tid];
    __syncthreads();

    const float4* __restrict__ w4 =
        (const float4*)(fc1_w + (size_t)c * L_DIM + p * 256);
    const float4* __restrict__ r4 = (const float4*)(row + p * 256);
    float a = 0.f;
#pragma unroll 8
    for (int k4 = 0; k4 < 64; ++k4) {
        float4 wv = w4[k4];
        float4 rv = r4[k4];
        a = fmaf(wv.x, rv.x, a);
        a = fmaf(wv.y, rv.y, a);
        a = fmaf(wv.z, rv.z, a);
        a = fmaf(wv.w, rv.w, a);
    }
    fcred[tid] = a;
    __syncthreads();
    if (tid < NUM_CLASSES)
        out[(size_t)b * NUM_CLASSES + tid] =
            fcred[tid] + fcred[tid + 128] + fc1_b[tid];
}

extern "C" void kernel_launch(void* const* d_in, const int* in_sizes, int n_in,
                              void* d_out, int out_size, void* d_ws, size_t ws_size,
                              hipStream_t stream) {
    const float* H     = (const float*)d_in[0];
    const float* att   = (const float*)d_in[1];
    const int*   batch = (const int*)d_in[2];
    const float* fc1_w = (const float*)d_in[3];
    const float* fc1_b = (const float*)d_in[4];
    float* out = (float*)d_out;

    char* ws = (char*)d_ws;
    int*   start    = (int*)ws;              // 2052 B
    float* bag_feat = (float*)(ws + 4096);   // 512*512 floats = 1 MB

    boundaries_kernel<<<N_INST / 256, 256, 0, stream>>>(batch, start);
    bag_accum_kernel<<<2 * BAG_NUM, 256, 0, stream>>>(H, att, start, bag_feat);
    fc_kernel<<<BAG_NUM, 256, 0, stream>>>(bag_feat, fc1_w, fc1_b, out);
}